// Round 3
// baseline (439.829 us; speedup 1.0000x reference)
//
#include <hip/hip_runtime.h>

// Problem constants (fixed by setup_inputs)
#define TB 16
#define NHEADS 16
#define HD 32
#define WS 8
#define SS 4

typedef __attribute__((ext_vector_type(8))) __bf16 bf16x8;
typedef __attribute__((ext_vector_type(4))) float f32x4;

// LDS layout (bytes), one (window,head) problem per 4-wave block:
//   [0,      5120)  Qs bf16 [64][40]  stride 80   -- overlaid by P after QK^T
//   [5120,  10240)  Ks bf16 [64][40]  stride 80   -- overlaid by P after QK^T
//   [0,      9216)  P  bf16 [64][72]  stride 144  (overlays Qs+Ks)
//   [10240, 14848)  Vt bf16 [32][72]  stride 144  (V transposed: [chan][token])
//   [14848, 15748)  Bs f32  [225]    (fallback path only)
#define OFF_Q 0
#define OFF_K 5120
#define OFF_P 0
#define OFF_V 10240
#define OFF_B 14848

// biasT[head][j][i] = rel_bias for query i, key j, head  (16*64*64 f32 = 256 KB)
__global__ void prep_bias(const float* __restrict__ bt, float* __restrict__ biasT) {
    const int t = blockIdx.x * 256 + threadIdx.x;   // 0..65535
    const int head = t >> 12;
    const int j = (t >> 6) & 63;
    const int i = t & 63;
    const int idx = ((i >> 3) - (j >> 3) + 7) * 15 + ((i & 7) - (j & 7) + 7);
    biasT[t] = bt[idx * NHEADS + head];
}

template<bool PRE>
__global__ __launch_bounds__(256, 8)
void swin_attn_mfma(const float* __restrict__ q,
                    const float* __restrict__ k,
                    const float* __restrict__ v,
                    const float* __restrict__ bias_table,
                    const float* __restrict__ biasT,
                    float* __restrict__ out)
{
    __shared__ __align__(16) char smem[15760];
    char* sQ = smem + OFF_Q;
    char* sK = smem + OFF_K;
    char* sP = smem + OFF_P;
    char* sV = smem + OFF_V;
    float* sB = (float*)(smem + OFF_B);

    const int blk  = blockIdx.x;            // 0..16383
    const int head = blk & (NHEADS - 1);
    const int win  = (blk >> 4) & 63;
    const int b    = blk >> 10;
    const int wh   = win >> 3;
    const int ww   = win & 7;

    const int tid  = threadIdx.x;           // 0..255
    const int wave = tid >> 6;              // 0..3  (tile row band mt)
    const int lane = tid & 63;
    const int quad = lane >> 4, lm = lane & 15;

    // ---- Phase 0: parallel staging. wave0=Q(scaled), wave1=K, wave2/3=V^T halves
    {
        const int ih = lane >> 3, iw = lane & 7;   // lane = token this lane stages
        const int gh = (wh * WS + ih + SS) & 63;
        const int gw = (ww * WS + iw + SS) & 63;
        const size_t rowbase = (((size_t)b * 64 + gh) * 64 + gw) * 512 + (size_t)head * HD;

        if (wave == 0) {
            const float scale = 0.17677669529663687f;  // 32^-0.5
            const float4* qrow = (const float4*)(q + rowbase);
            #pragma unroll
            for (int t = 0; t < 4; ++t) {
                float4 a = qrow[2 * t], c = qrow[2 * t + 1];
                bf16x8 w;
                w[0] = (__bf16)(a.x * scale); w[1] = (__bf16)(a.y * scale);
                w[2] = (__bf16)(a.z * scale); w[3] = (__bf16)(a.w * scale);
                w[4] = (__bf16)(c.x * scale); w[5] = (__bf16)(c.y * scale);
                w[6] = (__bf16)(c.z * scale); w[7] = (__bf16)(c.w * scale);
                *(bf16x8*)(sQ + lane * 80 + 16 * t) = w;
            }
        } else if (wave == 1) {
            const float4* krow = (const float4*)(k + rowbase);
            #pragma unroll
            for (int t = 0; t < 4; ++t) {
                float4 a = krow[2 * t], c = krow[2 * t + 1];
                bf16x8 w;
                w[0] = (__bf16)a.x; w[1] = (__bf16)a.y;
                w[2] = (__bf16)a.z; w[3] = (__bf16)a.w;
                w[4] = (__bf16)c.x; w[5] = (__bf16)c.y;
                w[6] = (__bf16)c.z; w[7] = (__bf16)c.w;
                *(bf16x8*)(sK + lane * 80 + 16 * t) = w;
            }
        } else {
            const int t0 = (wave == 2) ? 0 : 4;
            const float4* vrow = (const float4*)(v + rowbase);
            #pragma unroll
            for (int t = 0; t < 4; ++t) {
                float4 x = vrow[t0 + t];
                const int ch = 4 * (t0 + t);
                *(__bf16*)(sV + (ch + 0) * 144 + lane * 2) = (__bf16)x.x;
                *(__bf16*)(sV + (ch + 1) * 144 + lane * 2) = (__bf16)x.y;
                *(__bf16*)(sV + (ch + 2) * 144 + lane * 2) = (__bf16)x.z;
                *(__bf16*)(sV + (ch + 3) * 144 + lane * 2) = (__bf16)x.w;
            }
            if (!PRE && wave == 3) {
                #pragma unroll
                for (int t = lane; t < 225; t += 64)
                    sB[t] = bias_table[t * NHEADS + head];
            }
        }
    }
    __syncthreads();

    // ---- Phase 1: S row-band = Q K^T. wave w computes tiles (mt=w, nt=0..3): 4 MFMAs ----
    bf16x8 qa = *(const bf16x8*)(sQ + (16 * wave + lm) * 80 + quad * 16);
    bf16x8 kb[4];
    #pragma unroll
    for (int nt = 0; nt < 4; ++nt)
        kb[nt] = *(const bf16x8*)(sK + (16 * nt + lm) * 80 + quad * 16);

    f32x4 S[4];
    #pragma unroll
    for (int nt = 0; nt < 4; ++nt) {
        f32x4 z = {0.f, 0.f, 0.f, 0.f};
        S[nt] = __builtin_amdgcn_mfma_f32_16x16x32_bf16(qa, kb[nt], z, 0, 0, 0);
    }
    // lane holds S[i][j]: i = 16*wave + 4*quad + r (r=reg), j = 16*nt + lm

    // ---- Phase 2: bias + mask + exp, in-register. Row sums deferred. ----
    const bool eh = (wh == 7), ew = (ww == 7);
    const int ihh  = 2 * wave + (quad >> 1);   // i>>3, constant per lane
    const int iww0 = 4 * (quad & 1);           // (i&7) - r
    const int jw   = lm & 7;                   // j&7, constant per lane
    const float* bTh = biasT + ((size_t)head << 12);   // [64 j][64 i]
    float part[4] = {0.f, 0.f, 0.f, 0.f};
    #pragma unroll
    for (int nt = 0; nt < 4; ++nt) {
        const int jh = 2 * nt + (lm >> 3);
        const bool okh = !eh || ((ihh < 4) == (jh < 4));
        f32x4 b4;
        if (PRE) {
            b4 = *(const f32x4*)(bTh + (16 * nt + lm) * 64 + 16 * wave + 4 * quad);
        } else {
            #pragma unroll
            for (int r = 0; r < 4; ++r)
                b4[r] = sB[(ihh - jh + 7) * 15 + (iww0 + r - jw + 7)];
        }
        #pragma unroll
        for (int r = 0; r < 4; ++r) {
            const int iww = iww0 + r;          // i&7
            float s = S[nt][r] + b4[r];
            bool ok = okh && (!ew || ((iww < 4) == (jw < 4)));
            float e = ok ? __expf(s) : 0.f;    // masked: exp(s-100) ~ 0
            S[nt][r] = e;
            part[r] += e;
        }
    }

    // ---- Phase 3: write unnormalized E (bf16, row-major) over Q/K region; ----
    // ---- row-sum shfl reduce overlaps the LDS writes; 1/l applied at O store ----
    __syncthreads();   // all waves' Q/K fragment reads done before P overwrites
    #pragma unroll
    for (int nt = 0; nt < 4; ++nt)
        #pragma unroll
        for (int r = 0; r < 4; ++r)
            *(__bf16*)(sP + (16 * wave + 4 * quad + r) * 144 + (16 * nt + lm) * 2)
                = (__bf16)S[nt][r];
    #pragma unroll
    for (int m = 1; m <= 8; m <<= 1)
        #pragma unroll
        for (int r = 0; r < 4; ++r)
            part[r] += __shfl_xor(part[r], m, 64);
    float rl[4];
    #pragma unroll
    for (int r = 0; r < 4; ++r)
        rl[r] = 1.f / part[r];
    __syncthreads();

    // ---- Phase 4: O row-band = E V. wave w computes tiles (mt=w, nt=0..1): 4 MFMAs ----
    bf16x8 pa0 = *(const bf16x8*)(sP + (16 * wave + lm) * 144 + quad * 16);
    bf16x8 pa1 = *(const bf16x8*)(sP + (16 * wave + lm) * 144 + 64 + quad * 16);
    bf16x8 vb[2][2];
    #pragma unroll
    for (int nt = 0; nt < 2; ++nt)
        #pragma unroll
        for (int ks = 0; ks < 2; ++ks)
            vb[nt][ks] = *(const bf16x8*)(sV + (16 * nt + lm) * 144 + ks * 64 + quad * 16);

    f32x4 O[2];
    #pragma unroll
    for (int nt = 0; nt < 2; ++nt) {
        f32x4 z = {0.f, 0.f, 0.f, 0.f};
        z = __builtin_amdgcn_mfma_f32_16x16x32_bf16(pa0, vb[nt][0], z, 0, 0, 0);
        O[nt] = __builtin_amdgcn_mfma_f32_16x16x32_bf16(pa1, vb[nt][1], z, 0, 0, 0);
    }

    // ---- Phase 5: store O * (1/l)  (row i = 16*wave+4*quad+r, col = 16*nt+lm) ----
    #pragma unroll
    for (int r = 0; r < 4; ++r) {
        const int i = 16 * wave + 4 * quad + r;
        const int ghh = (wh * WS + (i >> 3) + SS) & 63;
        const int gww = (ww * WS + (i & 7) + SS) & 63;
        float* rp = out + (((size_t)b * 64 + ghh) * 64 + gww) * 512 + (size_t)head * HD + lm;
        rp[0]  = O[0][r] * rl[r];
        rp[16] = O[1][r] * rl[r];
    }
}

extern "C" void kernel_launch(void* const* d_in, const int* in_sizes, int n_in,
                              void* d_out, int out_size, void* d_ws, size_t ws_size,
                              hipStream_t stream) {
    const float* q  = (const float*)d_in[0];
    const float* k  = (const float*)d_in[1];
    const float* v  = (const float*)d_in[2];
    const float* bt = (const float*)d_in[3];
    float* out = (float*)d_out;
    float* biasT = (float*)d_ws;

    const bool pre = (d_ws != nullptr) && (ws_size >= (size_t)NHEADS * 64 * 64 * sizeof(float));
    dim3 block(256);
    if (pre) {
        prep_bias<<<dim3(256), block, 0, stream>>>(bt, biasT);
        swin_attn_mfma<true><<<dim3(TB * 64 * NHEADS), block, 0, stream>>>(q, k, v, bt, biasT, out);
    } else {
        swin_attn_mfma<false><<<dim3(TB * 64 * NHEADS), block, 0, stream>>>(q, k, v, bt, biasT, out);
    }
}